// Round 10
// baseline (41943.567 us; speedup 1.0000x reference)
//
#include <hip/hip_runtime.h>
#include <hip/hip_bf16.h>

#define DD 512
#define LL 512
#define BB 64
#define NT 1536
#define MROWS (LL*BB)

typedef short short8 __attribute__((ext_vector_type(8)));
typedef float floatx4 __attribute__((ext_vector_type(4)));
union U4S8 { uint4 u4; short8 s8; };

static __device__ __forceinline__ unsigned short f2bf(float f) {
  unsigned int u = __float_as_uint(f);
  unsigned int r = (u + 0x7fffu + ((u >> 16) & 1u)) >> 16;
  return (unsigned short)r;
}
static __device__ __forceinline__ float bf2f(unsigned short s) {
  return __uint_as_float(((unsigned int)s) << 16);
}

// Pack Wc[s][512 k][1024 col] f32 -> B-fragments for the 16-wave register-resident
// scan. uint index U = ((s*16+w)*64 + ct*16+kf)*256 + lane*4 + u.
// col = w*64 + ct*16 + (lane&15); k = kf*32 + (lane>>4)*8 + 2u (+1 in hi half).
__global__ void pack_wc16_k(const float* __restrict__ Wc, unsigned int* __restrict__ Wp) {
  int U = blockIdx.x * 256 + threadIdx.x;      // [0, 4*16*64*256) = [0, 2^20)
  int u = U & 3;
  int lane = (U >> 2) & 63;
  int fi = (U >> 8) & 63;        // ct*16 + kf
  int ct = fi >> 4, kf = fi & 15;
  int sw = U >> 14;
  int w = sw & 15, s = sw >> 4;
  int col = w * 64 + ct * 16 + (lane & 15);
  int k = kf * 32 + (lane >> 4) * 8 + 2 * u;
  size_t base = (size_t)s * DD * 1024;
  float lo = Wc[base + (size_t)k * 1024 + col];
  float hi = Wc[base + (size_t)(k + 1) * 1024 + col];
  Wp[U] = (unsigned int)f2bf(lo) | ((unsigned int)f2bf(hi) << 16);
}

// Transpose Wx[s][512 k][1536 n] f32 -> Wxp[s][1536 n][512 k] bf16 (tiled).
__global__ __launch_bounds__(256)
void pack_wx_k(const float* __restrict__ W, unsigned short* __restrict__ Wxp) {
  __shared__ float t[64][65];
  int k0 = blockIdx.x * 64, n0 = blockIdx.y * 64, s = blockIdx.z;
  int tx = threadIdx.x & 63, ty = threadIdx.x >> 6;
  const float* Wb = W + (size_t)s * DD * NT;
#pragma unroll
  for (int i = 0; i < 16; ++i) {
    int k = ty * 16 + i;
    t[k][tx] = Wb[(size_t)(k0 + k) * NT + n0 + tx];
  }
  __syncthreads();
  unsigned short* Ob = Wxp + (size_t)s * NT * DD;
#pragma unroll
  for (int i = 0; i < 16; ++i) {
    int n = ty * 16 + i;
    Ob[(size_t)(n0 + n) * DD + k0 + tx] = f2bf(t[tx][n]);
  }
}

__global__ void gather_k(const int* __restrict__ xs, const float* __restrict__ emb,
                         float* __restrict__ x) {
  int i = blockIdx.x * 256 + threadIdx.x;
  int row = i >> 7;
  int col = i & 127;
  const float4* src = (const float4*)(emb + (size_t)xs[row] * DD);
  ((float4*)(x + (size_t)row * DD))[col] = src[col];
}

// ---------------- fallback fp32 GEMM (proven) ----------------
__global__ __launch_bounds__(256)
void gemm_k(const float* __restrict__ A, const float* __restrict__ W,
            const float* __restrict__ bias, unsigned short* __restrict__ C) {
  __shared__ float As[16][128];
  __shared__ float Bs[16][128];
  const int tid = threadIdx.x;
  const int tx = tid & 15;
  const int ty = tid >> 4;
  const int m0 = blockIdx.y * 128;
  const int n0 = blockIdx.x * 128;
  const int lm = tid >> 1;
  const int lk = (tid & 1) * 8;
  const int wk = tid >> 4;
  const int wn = (tid & 15) * 8;
  float acc[8][8];
#pragma unroll
  for (int i = 0; i < 8; ++i)
#pragma unroll
    for (int j = 0; j < 8; ++j) acc[i][j] = 0.f;
  for (int k0 = 0; k0 < DD; k0 += 16) {
    float4 a0 = *(const float4*)(A + (size_t)(m0 + lm) * DD + k0 + lk);
    float4 a1 = *(const float4*)(A + (size_t)(m0 + lm) * DD + k0 + lk + 4);
    float4 w0 = *(const float4*)(W + (size_t)(k0 + wk) * NT + n0 + wn);
    float4 w1 = *(const float4*)(W + (size_t)(k0 + wk) * NT + n0 + wn + 4);
    __syncthreads();
    As[lk + 0][lm] = a0.x; As[lk + 1][lm] = a0.y; As[lk + 2][lm] = a0.z; As[lk + 3][lm] = a0.w;
    As[lk + 4][lm] = a1.x; As[lk + 5][lm] = a1.y; As[lk + 6][lm] = a1.z; As[lk + 7][lm] = a1.w;
    *(float4*)&Bs[wk][wn] = w0;
    *(float4*)&Bs[wk][wn + 4] = w1;
    __syncthreads();
#pragma unroll
    for (int kk = 0; kk < 16; ++kk) {
      float a[8], w[8];
      *(float4*)&a[0] = *(const float4*)&As[kk][ty * 8];
      *(float4*)&a[4] = *(const float4*)&As[kk][ty * 8 + 4];
      *(float4*)&w[0] = *(const float4*)&Bs[kk][tx * 8];
      *(float4*)&w[4] = *(const float4*)&Bs[kk][tx * 8 + 4];
#pragma unroll
      for (int i = 0; i < 8; ++i)
#pragma unroll
        for (int j = 0; j < 8; ++j)
          acc[i][j] = fmaf(a[i], w[j], acc[i][j]);
    }
  }
#pragma unroll
  for (int i = 0; i < 8; ++i) {
    size_t rb = (size_t)(m0 + ty * 8 + i) * NT + n0 + tx * 8;
#pragma unroll
    for (int jv = 0; jv < 2; ++jv) {
      ushort4 v;
      v.x = f2bf(acc[i][jv*4+0] + bias[n0 + tx*8 + jv*4 + 0]);
      v.y = f2bf(acc[i][jv*4+1] + bias[n0 + tx*8 + jv*4 + 1]);
      v.z = f2bf(acc[i][jv*4+2] + bias[n0 + tx*8 + jv*4 + 2]);
      v.w = f2bf(acc[i][jv*4+3] + bias[n0 + tx*8 + jv*4 + 3]);
      *(ushort4*)(C + rb + jv*4) = v;
    }
  }
}

// ---------------- bf16 MFMA GEMM (proven round 7) ----------------
__global__ __launch_bounds__(256)
void gemm_m_k(const float* __restrict__ A, const unsigned short* __restrict__ Wt,
              const float* __restrict__ bias, unsigned short* __restrict__ C) {
  __shared__ unsigned short Al[128 * 40];
  __shared__ unsigned short Bl[128 * 40];
  const int tid = threadIdx.x;
  const int m0 = blockIdx.y * 128, n0 = blockIdx.x * 128;
  const int wave = tid >> 6, lane = tid & 63;
  const int wm = wave >> 1, wn = wave & 1;
  const int l15 = lane & 15, lh = lane >> 4;
  floatx4 acc[4][4];
#pragma unroll
  for (int i = 0; i < 4; ++i)
#pragma unroll
    for (int j = 0; j < 4; ++j) acc[i][j] = (floatx4){0.f, 0.f, 0.f, 0.f};

  const int ar = tid >> 3, ac = (tid & 7) * 4;
  const int br = tid >> 2, bc = (tid & 3) * 8;
#pragma unroll 1
  for (int k0 = 0; k0 < DD; k0 += 32) {
    float4 av[4];
#pragma unroll
    for (int p = 0; p < 4; ++p)
      av[p] = *(const float4*)(A + (size_t)(m0 + ar + p * 32) * DD + k0 + ac);
    uint4 bv0 = *(const uint4*)(Wt + (size_t)(n0 + br) * DD + k0 + bc);
    uint4 bv1 = *(const uint4*)(Wt + (size_t)(n0 + br + 64) * DD + k0 + bc);
    __syncthreads();
#pragma unroll
    for (int p = 0; p < 4; ++p) {
      ushort4 w4;
      w4.x = f2bf(av[p].x); w4.y = f2bf(av[p].y);
      w4.z = f2bf(av[p].z); w4.w = f2bf(av[p].w);
      *(ushort4*)&Al[(ar + p * 32) * 40 + ac] = w4;
    }
    *(uint4*)&Bl[br * 40 + bc] = bv0;
    *(uint4*)&Bl[(br + 64) * 40 + bc] = bv1;
    __syncthreads();
    U4S8 af[4], bfr[4];
#pragma unroll
    for (int mf = 0; mf < 4; ++mf)
      af[mf].u4 = *(const uint4*)&Al[(wm * 64 + mf * 16 + l15) * 40 + lh * 8];
#pragma unroll
    for (int nf = 0; nf < 4; ++nf)
      bfr[nf].u4 = *(const uint4*)&Bl[(wn * 64 + nf * 16 + l15) * 40 + lh * 8];
#pragma unroll
    for (int mf = 0; mf < 4; ++mf)
#pragma unroll
      for (int nf = 0; nf < 4; ++nf)
        acc[mf][nf] = __builtin_amdgcn_mfma_f32_16x16x32_bf16(
            af[mf].s8, bfr[nf].s8, acc[mf][nf], 0, 0, 0);
  }
#pragma unroll
  for (int nf = 0; nf < 4; ++nf) {
    int n = n0 + wn * 64 + nf * 16 + l15;
    float bn = bias[n];
#pragma unroll
    for (int mf = 0; mf < 4; ++mf) {
      int row = m0 + wm * 64 + mf * 16 + lh * 4;
      size_t base = (size_t)row * NT + n;
#pragma unroll
      for (int e = 0; e < 4; ++e)
        C[base + (size_t)e * NT] = f2bf(acc[mf][nf][e] + bn);
    }
  }
}

// ---------------- scan: 16 blocks x 4 batches, ZERO cross-block sync.
// Wave w holds B-frags for cols [w*64,w*64+64) x full K=512 in 256 VGPRs.
// c lives in f32 registers of gate-owner threads; bf16 copy staged in LDS
// for MFMA A-frags each step. Two __syncthreads per step, nothing else.
__global__ __launch_bounds__(1024)
void scan16_k(const unsigned short* __restrict__ gx,
              const uint4* __restrict__ Wsc,   // per-scan base, uint4 units
              const float* __restrict__ xin,
              float* __restrict__ hout,
              float* __restrict__ cbuf,        // [64][512] f32
              int reverse) {
  __shared__ __align__(16) unsigned short c_sh[4 * 528];  // [b][dim], stride 528
  __shared__ float pd[16 * 4 * 64];                       // [w][b][cl] 16 KiB
  const int tid = threadIdx.x;
  const int w = tid >> 6, lane = tid & 63;
  const int l15 = lane & 15, lq = lane >> 4;

  // ---- weights -> 256 VGPRs (64 B-frags: [ct 0..3][kf 0..15]) ----
  uint4 Wf[64];
  {
    const uint4* wb = Wsc + (size_t)w * 4096;
#pragma unroll
    for (int f = 0; f < 64; ++f) Wf[f] = wb[f * 64 + lane];
  }
  // ---- gate ownership: thread owns (gb, d0),(gb, d0+1); f32 c in regs ----
  const int gb = tid >> 8;            // 0..3 (uniform per wave)
  const int d0 = (tid & 255) * 2;     // even, 0..510
  const int gbatch = blockIdx.x * 4 + gb;
  float c0 = cbuf[gbatch * DD + d0];
  float c1 = cbuf[gbatch * DD + d0 + 1];
  *(unsigned int*)&c_sh[gb * 528 + d0] =
      (unsigned int)f2bf(c0) | ((unsigned int)f2bf(c1) << 16);
  __syncthreads();

  const int arow = lane & 3;          // A rows 4..15 mirror 0..3 (broadcast)
#pragma unroll 1
  for (int s = 0; s < LL; ++s) {
    const int t = reverse ? (LL - 1 - s) : s;
    const size_t rg = (size_t)t * BB + gbatch;
    // prefetch gate inputs (consumed after barrier; MFMA hides latency)
    unsigned int gi2 = *(const unsigned int*)(gx + rg * NT + d0);
    unsigned int gf2 = *(const unsigned int*)(gx + rg * NT + 512 + d0);
    unsigned int gc2 = *(const unsigned int*)(gx + rg * NT + 1024 + d0);
    float2 xv = *(const float2*)(xin + rg * DD + d0);
    // ---- A-frags from c_sh ----
    uint4 A[16];
#pragma unroll
    for (int kf = 0; kf < 16; ++kf)
      A[kf] = *(const uint4*)&c_sh[arow * 528 + kf * 32 + lq * 8];
    // ---- 64 MFMAs, fully reduced over K in-register ----
    floatx4 acc[4];
#pragma unroll
    for (int ct = 0; ct < 4; ++ct) acc[ct] = (floatx4){0.f, 0.f, 0.f, 0.f};
#pragma unroll
    for (int kf = 0; kf < 16; ++kf) {
      U4S8 a; a.u4 = A[kf];
#pragma unroll
      for (int ct = 0; ct < 4; ++ct) {
        U4S8 b; b.u4 = Wf[ct * 16 + kf];
        acc[ct] = __builtin_amdgcn_mfma_f32_16x16x32_bf16(a.s8, b.s8, acc[ct], 0, 0, 0);
      }
    }
    // ---- D rows 0..3 (= batches) live in lanes 0..15 ----
    if (lane < 16) {
#pragma unroll
      for (int ct = 0; ct < 4; ++ct)
#pragma unroll
        for (int e = 0; e < 4; ++e)
          pd[(w * 4 + e) * 64 + ct * 16 + l15] = acc[ct][e];
    }
    __syncthreads();     // pd ready; all A-reads of c_sh complete
    // ---- gate phase: cols d (i) and 512+d (f); owners w=d>>6 and 8+(d>>6) ----
    {
      int wi = d0 >> 6, cl = d0 & 63;
      float2 si = *(const float2*)&pd[(wi * 4 + gb) * 64 + cl];
      float2 sf = *(const float2*)&pd[((8 + wi) * 4 + gb) * 64 + cl];
      float i0 = 1.f / (1.f + __expf(-(bf2f((unsigned short)gi2) + si.x)));
      float i1 = 1.f / (1.f + __expf(-(bf2f((unsigned short)(gi2 >> 16)) + si.y)));
      float f0 = 1.f / (1.f + __expf(-(bf2f((unsigned short)gf2) + sf.x)));
      float f1 = 1.f / (1.f + __expf(-(bf2f((unsigned short)(gf2 >> 16)) + sf.y)));
      float cn0 = fmaf(f0, c0, i0 * bf2f((unsigned short)gc2));
      float cn1 = fmaf(f1, c1, i1 * bf2f((unsigned short)(gc2 >> 16)));
      c0 = cn0; c1 = cn1;
      float2 h;
      h.x = tanhf(cn0) + xv.x;
      h.y = tanhf(cn1) + xv.y;
      *(float2*)(hout + rg * DD + d0) = h;
      *(unsigned int*)&c_sh[gb * 528 + d0] =
          (unsigned int)f2bf(cn0) | ((unsigned int)f2bf(cn1) << 16);
    }
    __syncthreads();     // new c_sh visible for next step's A-frags
  }
  cbuf[gbatch * DD + d0] = c0;
  cbuf[gbatch * DD + d0 + 1] = c1;
}

extern "C" void kernel_launch(void* const* d_in, const int* in_sizes, int n_in,
                              void* d_out, int out_size, void* d_ws, size_t ws_size,
                              hipStream_t stream) {
  const int* xs = (const int*)d_in[0];
  const float* emb = (const float*)d_in[1];
  const float* Wx = (const float*)d_in[2];
  const float* Wc = (const float*)d_in[3];
  const float* bias = (const float*)d_in[4];
  float* out = (float*)d_out;
  char* ws = (char*)d_ws;

  unsigned short* gx = (unsigned short*)ws;                          // 96 MiB
  float* xB = (float*)(ws + (size_t)100663296);                      // 64 MiB
  unsigned int* Wp = (unsigned int*)(ws + (size_t)167772160);        // 4 MiB
  float* cbuf = (float*)(ws + (size_t)171966464);                    // 128 KiB
  unsigned short* Wxp = (unsigned short*)(ws + (size_t)172359680);   // 6 MiB
  const size_t NEED = 178651136ull;
  const bool use_mfma_gemm = (ws_size >= NEED);

  hipMemsetAsync(cbuf, 0, 131072, stream);
  pack_wc16_k<<<4096, 256, 0, stream>>>(Wc, Wp);
  if (use_mfma_gemm)
    pack_wx_k<<<dim3(8, 24, 4), 256, 0, stream>>>(Wx, Wxp);
  gather_k<<<MROWS * 128 / 256, 256, 0, stream>>>(xs, emb, out);

  for (int s = 0; s < 4; ++s) {
    const float* xin = (s % 2 == 0) ? out : xB;
    float* xout = (s % 2 == 0) ? xB : out;
    if (use_mfma_gemm)
      gemm_m_k<<<dim3(NT / 128, MROWS / 128), 256, 0, stream>>>(
          xin, Wxp + (size_t)s * NT * DD, bias + (size_t)s * NT, gx);
    else
      gemm_k<<<dim3(NT / 128, MROWS / 128), 256, 0, stream>>>(
          xin, Wx + (size_t)s * DD * NT, bias + (size_t)s * NT, gx);
    scan16_k<<<16, 1024, 0, stream>>>(
        gx, (const uint4*)(Wp + (size_t)s * 262144), xin, xout, cbuf, s & 1);
  }
}

// Round 11
// 9028.252 us; speedup vs baseline: 4.6458x; 4.6458x over previous
//
#include <hip/hip_runtime.h>
#include <hip/hip_bf16.h>

#define DD 512
#define LL 512
#define BB 64
#define NT 1536
#define MROWS (LL*BB)

typedef short short8 __attribute__((ext_vector_type(8)));
typedef float floatx4 __attribute__((ext_vector_type(4)));
union U4S8 { uint4 u4; short8 s8; };
typedef unsigned long long ull;

static __device__ __forceinline__ unsigned short f2bf(float f) {
  unsigned int u = __float_as_uint(f);
  unsigned int r = (u + 0x7fffu + ((u >> 16) & 1u)) >> 16;
  return (unsigned short)r;
}
static __device__ __forceinline__ float bf2f(unsigned short s) {
  return __uint_as_float(((unsigned int)s) << 16);
}

// Pack Wc[s][512 k][1024 col] f32 -> MFMA B-fragments, bf16 pairs (round-5 proven layout).
__global__ void pack_wc_k(const float* __restrict__ Wc, unsigned int* __restrict__ Wp) {
  int U = blockIdx.x * 256 + threadIdx.x;      // [0, 4*8*32768)
  int sdg = U >> 15;
  int s = sdg >> 3, dg = sdg & 7;
  int r = U & 32767;
  int u = r & 3;
  int lane = (r >> 2) & 63;
  int fidx = r >> 8;            // 0..127 = w*16 + ct*2 + kt
  int kt = fidx & 1;
  int ct = (fidx >> 1) & 7;
  int w = fidx >> 4;
  int k = w * 64 + kt * 32 + 8 * (lane >> 4) + 2 * u;
  int cl = ct * 16 + (lane & 15);
  int gcol = (cl >> 6) * 512 + dg * 64 + (cl & 63);
  size_t base = (size_t)s * DD * 1024;
  float lo = Wc[base + (size_t)k * 1024 + gcol];
  float hi = Wc[base + (size_t)(k + 1) * 1024 + gcol];
  Wp[U] = (unsigned int)f2bf(lo) | ((unsigned int)f2bf(hi) << 16);
}

// Transpose Wx[s][512 k][1536 n] f32 -> Wxp[s][1536 n][512 k] bf16 (tiled).
__global__ __launch_bounds__(256)
void pack_wx_k(const float* __restrict__ W, unsigned short* __restrict__ Wxp) {
  __shared__ float t[64][65];
  int k0 = blockIdx.x * 64, n0 = blockIdx.y * 64, s = blockIdx.z;
  int tx = threadIdx.x & 63, ty = threadIdx.x >> 6;
  const float* Wb = W + (size_t)s * DD * NT;
#pragma unroll
  for (int i = 0; i < 16; ++i) {
    int k = ty * 16 + i;
    t[k][tx] = Wb[(size_t)(k0 + k) * NT + n0 + tx];
  }
  __syncthreads();
  unsigned short* Ob = Wxp + (size_t)s * NT * DD;
#pragma unroll
  for (int i = 0; i < 16; ++i) {
    int n = ty * 16 + i;
    Ob[(size_t)(n0 + n) * DD + k0 + tx] = f2bf(t[tx][n]);
  }
}

__global__ void gather_k(const int* __restrict__ xs, const float* __restrict__ emb,
                         float* __restrict__ x) {
  int i = blockIdx.x * 256 + threadIdx.x;
  int row = i >> 7;
  int col = i & 127;
  const float4* src = (const float4*)(emb + (size_t)xs[row] * DD);
  ((float4*)(x + (size_t)row * DD))[col] = src[col];
}

// ---------------- fallback fp32 GEMM (proven) ----------------
__global__ __launch_bounds__(256)
void gemm_k(const float* __restrict__ A, const float* __restrict__ W,
            const float* __restrict__ bias, unsigned short* __restrict__ C) {
  __shared__ float As[16][128];
  __shared__ float Bs[16][128];
  const int tid = threadIdx.x;
  const int tx = tid & 15;
  const int ty = tid >> 4;
  const int m0 = blockIdx.y * 128;
  const int n0 = blockIdx.x * 128;
  const int lm = tid >> 1;
  const int lk = (tid & 1) * 8;
  const int wk = tid >> 4;
  const int wn = (tid & 15) * 8;
  float acc[8][8];
#pragma unroll
  for (int i = 0; i < 8; ++i)
#pragma unroll
    for (int j = 0; j < 8; ++j) acc[i][j] = 0.f;
  for (int k0 = 0; k0 < DD; k0 += 16) {
    float4 a0 = *(const float4*)(A + (size_t)(m0 + lm) * DD + k0 + lk);
    float4 a1 = *(const float4*)(A + (size_t)(m0 + lm) * DD + k0 + lk + 4);
    float4 w0 = *(const float4*)(W + (size_t)(k0 + wk) * NT + n0 + wn);
    float4 w1 = *(const float4*)(W + (size_t)(k0 + wk) * NT + n0 + wn + 4);
    __syncthreads();
    As[lk + 0][lm] = a0.x; As[lk + 1][lm] = a0.y; As[lk + 2][lm] = a0.z; As[lk + 3][lm] = a0.w;
    As[lk + 4][lm] = a1.x; As[lk + 5][lm] = a1.y; As[lk + 6][lm] = a1.z; As[lk + 7][lm] = a1.w;
    *(float4*)&Bs[wk][wn] = w0;
    *(float4*)&Bs[wk][wn + 4] = w1;
    __syncthreads();
#pragma unroll
    for (int kk = 0; kk < 16; ++kk) {
      float a[8], w[8];
      *(float4*)&a[0] = *(const float4*)&As[kk][ty * 8];
      *(float4*)&a[4] = *(const float4*)&As[kk][ty * 8 + 4];
      *(float4*)&w[0] = *(const float4*)&Bs[kk][tx * 8];
      *(float4*)&w[4] = *(const float4*)&Bs[kk][tx * 8 + 4];
#pragma unroll
      for (int i = 0; i < 8; ++i)
#pragma unroll
        for (int j = 0; j < 8; ++j)
          acc[i][j] = fmaf(a[i], w[j], acc[i][j]);
    }
  }
#pragma unroll
  for (int i = 0; i < 8; ++i) {
    size_t rb = (size_t)(m0 + ty * 8 + i) * NT + n0 + tx * 8;
#pragma unroll
    for (int jv = 0; jv < 2; ++jv) {
      ushort4 v;
      v.x = f2bf(acc[i][jv*4+0] + bias[n0 + tx*8 + jv*4 + 0]);
      v.y = f2bf(acc[i][jv*4+1] + bias[n0 + tx*8 + jv*4 + 1]);
      v.z = f2bf(acc[i][jv*4+2] + bias[n0 + tx*8 + jv*4 + 2]);
      v.w = f2bf(acc[i][jv*4+3] + bias[n0 + tx*8 + jv*4 + 3]);
      *(ushort4*)(C + rb + jv*4) = v;
    }
  }
}

// ---------------- bf16 MFMA GEMM (proven round 7) ----------------
__global__ __launch_bounds__(256)
void gemm_m_k(const float* __restrict__ A, const unsigned short* __restrict__ Wt,
              const float* __restrict__ bias, unsigned short* __restrict__ C) {
  __shared__ unsigned short Al[128 * 40];
  __shared__ unsigned short Bl[128 * 40];
  const int tid = threadIdx.x;
  const int m0 = blockIdx.y * 128, n0 = blockIdx.x * 128;
  const int wave = tid >> 6, lane = tid & 63;
  const int wm = wave >> 1, wn = wave & 1;
  const int l15 = lane & 15, lh = lane >> 4;
  floatx4 acc[4][4];
#pragma unroll
  for (int i = 0; i < 4; ++i)
#pragma unroll
    for (int j = 0; j < 4; ++j) acc[i][j] = (floatx4){0.f, 0.f, 0.f, 0.f};

  const int ar = tid >> 3, ac = (tid & 7) * 4;
  const int br = tid >> 2, bc = (tid & 3) * 8;
#pragma unroll 1
  for (int k0 = 0; k0 < DD; k0 += 32) {
    float4 av[4];
#pragma unroll
    for (int p = 0; p < 4; ++p)
      av[p] = *(const float4*)(A + (size_t)(m0 + ar + p * 32) * DD + k0 + ac);
    uint4 bv0 = *(const uint4*)(Wt + (size_t)(n0 + br) * DD + k0 + bc);
    uint4 bv1 = *(const uint4*)(Wt + (size_t)(n0 + br + 64) * DD + k0 + bc);
    __syncthreads();
#pragma unroll
    for (int p = 0; p < 4; ++p) {
      ushort4 w4;
      w4.x = f2bf(av[p].x); w4.y = f2bf(av[p].y);
      w4.z = f2bf(av[p].z); w4.w = f2bf(av[p].w);
      *(ushort4*)&Al[(ar + p * 32) * 40 + ac] = w4;
    }
    *(uint4*)&Bl[br * 40 + bc] = bv0;
    *(uint4*)&Bl[(br + 64) * 40 + bc] = bv1;
    __syncthreads();
    U4S8 af[4], bfr[4];
#pragma unroll
    for (int mf = 0; mf < 4; ++mf)
      af[mf].u4 = *(const uint4*)&Al[(wm * 64 + mf * 16 + l15) * 40 + lh * 8];
#pragma unroll
    for (int nf = 0; nf < 4; ++nf)
      bfr[nf].u4 = *(const uint4*)&Bl[(wn * 64 + nf * 16 + l15) * 40 + lh * 8];
#pragma unroll
    for (int mf = 0; mf < 4; ++mf)
#pragma unroll
      for (int nf = 0; nf < 4; ++nf)
        acc[mf][nf] = __builtin_amdgcn_mfma_f32_16x16x32_bf16(
            af[mf].s8, bfr[nf].s8, acc[mf][nf], 0, 0, 0);
  }
#pragma unroll
  for (int nf = 0; nf < 4; ++nf) {
    int n = n0 + wn * 64 + nf * 16 + l15;
    float bn = bias[n];
#pragma unroll
    for (int mf = 0; mf < 4; ++mf) {
      int row = m0 + wm * 64 + mf * 16 + lh * 4;
      size_t base = (size_t)row * NT + n;
#pragma unroll
      for (int e = 0; e < 4; ++e)
        C[base + (size_t)e * NT] = f2bf(acc[mf][nf][e] + bn);
    }
  }
}

// ---------------- scan: round-7 structure, lean 3-hop exchange.
// Wave w (= batch w of bg) publishes its 128B slice -> vmcnt(0) -> per-wave tag.
// Consumer wave w (= K-slice w) polls 8 contiguous tags of partner block (bg,w),
// then loads A-frags directly (round-7 addressing). One barrier/step (pd dbuf).
__global__ __launch_bounds__(512, 1)
void scan_k(const unsigned short* __restrict__ gx,
            const uint4* __restrict__ Wsc,
            const float* __restrict__ xin,
            float* __restrict__ hout,
            float* __restrict__ cbuf,           // [64][512] f32
            unsigned int* __restrict__ xbt,     // [2][64][256] u32 (bf16-pair c)
            unsigned int* __restrict__ tags,    // [8 bg][8 dg][8 wave] monotonic
            int reverse, unsigned int step_base) {
  __shared__ float pd[2][8192];                 // 64 KiB, step-parity double buffer
  const int tid = threadIdx.x;
  const int bg = blockIdx.x & 7;
  const int dg = blockIdx.x >> 3;
  const int lane = tid & 63;
  const int w = tid >> 6;
  const int batch = bg * 8 + w;
  const int dim = dg * 64 + lane;

  uint4 Wf[16];
  {
    const uint4* ws = Wsc + (size_t)dg * 8192;
#pragma unroll
    for (int f = 0; f < 16; ++f)
      Wf[f] = ws[(size_t)(w * 16 + f) * 64 + lane];
  }
  float c_reg = cbuf[batch * DD + dim];
  int t0 = reverse ? (LL - 1) : 0;
  size_t r0 = (size_t)t0 * BB + batch;
  float g_i = bf2f(gx[r0 * NT + dim]);
  float g_f = bf2f(gx[r0 * NT + 512 + dim]);
  float g_c = bf2f(gx[r0 * NT + 1024 + dim]);
  float x_v = xin[r0 * DD + dim];
  const int arow = lane & 7, lh = lane >> 4;
  const int aiB = (bg * 8 + arow) * 128 + w * 16 + 2 * lh;   // ull units in parity

  U4S8 A0, A1;
  // ---- prologue: poll >= step_base (trivially satisfied), load A for step 0 (parity 1) ----
  {
    for (;;) {
      unsigned int tv = 0xffffffffu;
      if (lane < 8)
        tv = __hip_atomic_load(&tags[bg * 64 + w * 8 + lane], __ATOMIC_RELAXED, __HIP_MEMORY_SCOPE_AGENT);
      bool ok = (lane < 8) ? (tv >= step_base) : true;
      if (__all(ok)) break;
      __builtin_amdgcn_s_sleep(1);
    }
    asm volatile("" ::: "memory");
    const ull* src = (const ull*)xbt + 8192 + aiB;
    ull v0 = __hip_atomic_load(src + 0, __ATOMIC_RELAXED, __HIP_MEMORY_SCOPE_AGENT);
    ull v1 = __hip_atomic_load(src + 1, __ATOMIC_RELAXED, __HIP_MEMORY_SCOPE_AGENT);
    ull v2 = __hip_atomic_load(src + 8, __ATOMIC_RELAXED, __HIP_MEMORY_SCOPE_AGENT);
    ull v3 = __hip_atomic_load(src + 9, __ATOMIC_RELAXED, __HIP_MEMORY_SCOPE_AGENT);
    A0.u4 = make_uint4((unsigned int)v0, (unsigned int)(v0 >> 32),
                       (unsigned int)v1, (unsigned int)(v1 >> 32));
    A1.u4 = make_uint4((unsigned int)v2, (unsigned int)(v2 >> 32),
                       (unsigned int)v3, (unsigned int)(v3 >> 32));
  }

#pragma unroll 1
  for (int s = 0; s < LL; ++s) {
    // ---- MFMA partials over this wave's K-slice ----
    float* pds = pd[s & 1];
#pragma unroll
    for (int ct = 0; ct < 8; ++ct) {
      U4S8 B0, B1; B0.u4 = Wf[ct * 2]; B1.u4 = Wf[ct * 2 + 1];
      floatx4 acc = __builtin_amdgcn_mfma_f32_16x16x32_bf16(
          A0.s8, B0.s8, (floatx4){0.f, 0.f, 0.f, 0.f}, 0, 0, 0);
      acc = __builtin_amdgcn_mfma_f32_16x16x32_bf16(A1.s8, B1.s8, acc, 0, 0, 0);
      if (lane < 32) {
        int colb = ct * 16 + (lane & 15);
        int rb = (lane >> 4) * 4;
#pragma unroll
        for (int e = 0; e < 4; ++e)
          pds[(w * 8 + rb + e) * 128 + colb] = acc[e];
      }
    }
    __syncthreads();                     // pd ready (dbuf -> only barrier per step)
    // ---- reduce + gates (wave w owns batch bg*8+w, dim dg*64+lane) ----
    float gsi = 0.f, gsf = 0.f;
#pragma unroll
    for (int ww = 0; ww < 8; ++ww) {
      gsi += pds[(ww * 8 + w) * 128 + lane];
      gsf += pds[(ww * 8 + w) * 128 + 64 + lane];
    }
    float iv = 1.f / (1.f + __expf(-(g_i + gsi)));
    float fv = 1.f / (1.f + __expf(-(g_f + gsf)));
    float cn = fmaf(fv, c_reg, iv * g_c);
    c_reg = cn;
    // ---- publish (4B packed, even lanes; 128B contiguous per wave) ----
    unsigned int vb = (unsigned int)f2bf(cn);
    unsigned int ob = (unsigned int)__shfl_down((int)vb, 1);
    if ((lane & 1) == 0)
      __hip_atomic_store(xbt + (size_t)(s & 1) * 16384 + batch * 256 + dg * 32 + (lane >> 1),
                         vb | (ob << 16), __ATOMIC_RELAXED, __HIP_MEMORY_SCOPE_AGENT);
    // drain ONLY the publish (nothing else outstanding in this wave here)
    asm volatile("s_waitcnt vmcnt(0)" ::: "memory");
    if (lane == 0)
      __hip_atomic_store(&tags[bg * 64 + dg * 8 + w], step_base + (unsigned int)s + 1u,
                         __ATOMIC_RELAXED, __HIP_MEMORY_SCOPE_AGENT);
    // ---- off-critical tail: hout + next-step prefetch (overlaps partner latency) ----
    int t = reverse ? (LL - 1 - s) : s;
    size_t rowg = (size_t)t * BB + batch;
    hout[rowg * DD + dim] = tanhf(cn) + x_v;
    int sn = (s + 1 < LL) ? s + 1 : s;
    int tn = reverse ? (LL - 1 - sn) : sn;
    size_t rn = (size_t)tn * BB + batch;
    g_i = bf2f(gx[rn * NT + dim]);
    g_f = bf2f(gx[rn * NT + 512 + dim]);
    g_c = bf2f(gx[rn * NT + 1024 + dim]);
    x_v = xin[rn * DD + dim];
    // ---- poll partner block (bg, w)'s 8 tags; load A for step s+1 (parity s&1) ----
    if (s + 1 < LL) {
      unsigned int need = step_base + (unsigned int)s + 1u;
      for (;;) {
        unsigned int tv = 0xffffffffu;
        if (lane < 8)
          tv = __hip_atomic_load(&tags[bg * 64 + w * 8 + lane], __ATOMIC_RELAXED, __HIP_MEMORY_SCOPE_AGENT);
        bool ok = (lane < 8) ? (tv >= need) : true;
        if (__all(ok)) break;
        __builtin_amdgcn_s_sleep(1);
      }
      asm volatile("" ::: "memory");
      const ull* src = (const ull*)xbt + (size_t)(s & 1) * 8192 + aiB;
      ull v0 = __hip_atomic_load(src + 0, __ATOMIC_RELAXED, __HIP_MEMORY_SCOPE_AGENT);
      ull v1 = __hip_atomic_load(src + 1, __ATOMIC_RELAXED, __HIP_MEMORY_SCOPE_AGENT);
      ull v2 = __hip_atomic_load(src + 8, __ATOMIC_RELAXED, __HIP_MEMORY_SCOPE_AGENT);
      ull v3 = __hip_atomic_load(src + 9, __ATOMIC_RELAXED, __HIP_MEMORY_SCOPE_AGENT);
      A0.u4 = make_uint4((unsigned int)v0, (unsigned int)(v0 >> 32),
                         (unsigned int)v1, (unsigned int)(v1 >> 32));
      A1.u4 = make_uint4((unsigned int)v2, (unsigned int)(v2 >> 32),
                         (unsigned int)v3, (unsigned int)(v3 >> 32));
    }
  }
  cbuf[batch * DD + dim] = c_reg;
}

extern "C" void kernel_launch(void* const* d_in, const int* in_sizes, int n_in,
                              void* d_out, int out_size, void* d_ws, size_t ws_size,
                              hipStream_t stream) {
  const int* xs = (const int*)d_in[0];
  const float* emb = (const float*)d_in[1];
  const float* Wx = (const float*)d_in[2];
  const float* Wc = (const float*)d_in[3];
  const float* bias = (const float*)d_in[4];
  float* out = (float*)d_out;
  char* ws = (char*)d_ws;

  unsigned short* gx = (unsigned short*)ws;                          // 96 MiB
  float* xB = (float*)(ws + (size_t)100663296);                      // 64 MiB
  unsigned int* Wp = (unsigned int*)(ws + (size_t)167772160);        // 4 MiB
  float* cbuf = (float*)(ws + (size_t)171966464);                    // 128 KiB
  unsigned int* xbt = (unsigned int*)(ws + (size_t)172097536);       // 128 KiB
  unsigned int* tags = (unsigned int*)(ws + (size_t)172228608);      // 2 KiB
  unsigned short* Wxp = (unsigned short*)(ws + (size_t)172230656);   // 6 MiB
  const size_t NEED = 178522112ull;
  const bool use_mfma_gemm = (ws_size >= NEED);

  hipMemsetAsync(cbuf, 0, 131072, stream);
  hipMemsetAsync(xbt, 0, 131072, stream);    // bf16(c0)=0 seeds both parities
  hipMemsetAsync(tags, 0, 2048, stream);
  pack_wc_k<<<4096, 256, 0, stream>>>(Wc, Wp);
  if (use_mfma_gemm)
    pack_wx_k<<<dim3(8, 24, 4), 256, 0, stream>>>(Wx, Wxp);
  gather_k<<<MROWS * 128 / 256, 256, 0, stream>>>(xs, emb, out);

  for (int s = 0; s < 4; ++s) {
    const float* xin = (s % 2 == 0) ? out : xB;
    float* xout = (s % 2 == 0) ? xB : out;
    if (use_mfma_gemm)
      gemm_m_k<<<dim3(NT / 128, MROWS / 128), 256, 0, stream>>>(
          xin, Wxp + (size_t)s * NT * DD, bias + (size_t)s * NT, gx);
    else
      gemm_k<<<dim3(NT / 128, MROWS / 128), 256, 0, stream>>>(
          xin, Wx + (size_t)s * DD * NT, bias + (size_t)s * NT, gx);
    scan_k<<<64, 512, 0, stream>>>(
        gx, (const uint4*)(Wp + (size_t)s * 262144), xin, xout, cbuf, xbt, tags,
        s & 1, (unsigned int)(s * 512));
  }
}

// Round 12
// 5812.063 us; speedup vs baseline: 7.2166x; 1.5534x over previous
//
#include <hip/hip_runtime.h>
#include <hip/hip_bf16.h>

#define DD 512
#define LL 512
#define BB 64
#define NT 1536
#define MROWS (LL*BB)

typedef short short8 __attribute__((ext_vector_type(8)));
typedef float floatx4 __attribute__((ext_vector_type(4)));
union U4S8 { uint4 u4; short8 s8; };
typedef unsigned long long ull;

static __device__ __forceinline__ unsigned short f2bf(float f) {
  unsigned int u = __float_as_uint(f);
  unsigned int r = (u + 0x7fffu + ((u >> 16) & 1u)) >> 16;
  return (unsigned short)r;
}
static __device__ __forceinline__ float bf2f(unsigned short s) {
  return __uint_as_float(((unsigned int)s) << 16);
}

// Pack Wc[s][512 k][1024 col] f32 -> MFMA B-fragments, bf16 pairs (round-5 proven layout).
__global__ void pack_wc_k(const float* __restrict__ Wc, unsigned int* __restrict__ Wp) {
  int U = blockIdx.x * 256 + threadIdx.x;      // [0, 4*8*32768)
  int sdg = U >> 15;
  int s = sdg >> 3, dg = sdg & 7;
  int r = U & 32767;
  int u = r & 3;
  int lane = (r >> 2) & 63;
  int fidx = r >> 8;            // 0..127 = w*16 + ct*2 + kt
  int kt = fidx & 1;
  int ct = (fidx >> 1) & 7;
  int w = fidx >> 4;
  int k = w * 64 + kt * 32 + 8 * (lane >> 4) + 2 * u;
  int cl = ct * 16 + (lane & 15);
  int gcol = (cl >> 6) * 512 + dg * 64 + (cl & 63);
  size_t base = (size_t)s * DD * 1024;
  float lo = Wc[base + (size_t)k * 1024 + gcol];
  float hi = Wc[base + (size_t)(k + 1) * 1024 + gcol];
  Wp[U] = (unsigned int)f2bf(lo) | ((unsigned int)f2bf(hi) << 16);
}

// Transpose Wx[s][512 k][1536 n] f32 -> Wxp[s][1536 n][512 k] bf16 (tiled).
__global__ __launch_bounds__(256)
void pack_wx_k(const float* __restrict__ W, unsigned short* __restrict__ Wxp) {
  __shared__ float t[64][65];
  int k0 = blockIdx.x * 64, n0 = blockIdx.y * 64, s = blockIdx.z;
  int tx = threadIdx.x & 63, ty = threadIdx.x >> 6;
  const float* Wb = W + (size_t)s * DD * NT;
#pragma unroll
  for (int i = 0; i < 16; ++i) {
    int k = ty * 16 + i;
    t[k][tx] = Wb[(size_t)(k0 + k) * NT + n0 + tx];
  }
  __syncthreads();
  unsigned short* Ob = Wxp + (size_t)s * NT * DD;
#pragma unroll
  for (int i = 0; i < 16; ++i) {
    int n = ty * 16 + i;
    Ob[(size_t)(n0 + n) * DD + k0 + tx] = f2bf(t[tx][n]);
  }
}

__global__ void gather_k(const int* __restrict__ xs, const float* __restrict__ emb,
                         float* __restrict__ x) {
  int i = blockIdx.x * 256 + threadIdx.x;
  int row = i >> 7;
  int col = i & 127;
  const float4* src = (const float4*)(emb + (size_t)xs[row] * DD);
  ((float4*)(x + (size_t)row * DD))[col] = src[col];
}

// ---------------- fallback fp32 GEMM (proven) ----------------
__global__ __launch_bounds__(256)
void gemm_k(const float* __restrict__ A, const float* __restrict__ W,
            const float* __restrict__ bias, unsigned short* __restrict__ C) {
  __shared__ float As[16][128];
  __shared__ float Bs[16][128];
  const int tid = threadIdx.x;
  const int tx = tid & 15;
  const int ty = tid >> 4;
  const int m0 = blockIdx.y * 128;
  const int n0 = blockIdx.x * 128;
  const int lm = tid >> 1;
  const int lk = (tid & 1) * 8;
  const int wk = tid >> 4;
  const int wn = (tid & 15) * 8;
  float acc[8][8];
#pragma unroll
  for (int i = 0; i < 8; ++i)
#pragma unroll
    for (int j = 0; j < 8; ++j) acc[i][j] = 0.f;
  for (int k0 = 0; k0 < DD; k0 += 16) {
    float4 a0 = *(const float4*)(A + (size_t)(m0 + lm) * DD + k0 + lk);
    float4 a1 = *(const float4*)(A + (size_t)(m0 + lm) * DD + k0 + lk + 4);
    float4 w0 = *(const float4*)(W + (size_t)(k0 + wk) * NT + n0 + wn);
    float4 w1 = *(const float4*)(W + (size_t)(k0 + wk) * NT + n0 + wn + 4);
    __syncthreads();
    As[lk + 0][lm] = a0.x; As[lk + 1][lm] = a0.y; As[lk + 2][lm] = a0.z; As[lk + 3][lm] = a0.w;
    As[lk + 4][lm] = a1.x; As[lk + 5][lm] = a1.y; As[lk + 6][lm] = a1.z; As[lk + 7][lm] = a1.w;
    *(float4*)&Bs[wk][wn] = w0;
    *(float4*)&Bs[wk][wn + 4] = w1;
    __syncthreads();
#pragma unroll
    for (int kk = 0; kk < 16; ++kk) {
      float a[8], w[8];
      *(float4*)&a[0] = *(const float4*)&As[kk][ty * 8];
      *(float4*)&a[4] = *(const float4*)&As[kk][ty * 8 + 4];
      *(float4*)&w[0] = *(const float4*)&Bs[kk][tx * 8];
      *(float4*)&w[4] = *(const float4*)&Bs[kk][tx * 8 + 4];
#pragma unroll
      for (int i = 0; i < 8; ++i)
#pragma unroll
        for (int j = 0; j < 8; ++j)
          acc[i][j] = fmaf(a[i], w[j], acc[i][j]);
    }
  }
#pragma unroll
  for (int i = 0; i < 8; ++i) {
    size_t rb = (size_t)(m0 + ty * 8 + i) * NT + n0 + tx * 8;
#pragma unroll
    for (int jv = 0; jv < 2; ++jv) {
      ushort4 v;
      v.x = f2bf(acc[i][jv*4+0] + bias[n0 + tx*8 + jv*4 + 0]);
      v.y = f2bf(acc[i][jv*4+1] + bias[n0 + tx*8 + jv*4 + 1]);
      v.z = f2bf(acc[i][jv*4+2] + bias[n0 + tx*8 + jv*4 + 2]);
      v.w = f2bf(acc[i][jv*4+3] + bias[n0 + tx*8 + jv*4 + 3]);
      *(ushort4*)(C + rb + jv*4) = v;
    }
  }
}

// ---------------- bf16 MFMA GEMM (proven round 7) ----------------
__global__ __launch_bounds__(256)
void gemm_m_k(const float* __restrict__ A, const unsigned short* __restrict__ Wt,
              const float* __restrict__ bias, unsigned short* __restrict__ C) {
  __shared__ unsigned short Al[128 * 40];
  __shared__ unsigned short Bl[128 * 40];
  const int tid = threadIdx.x;
  const int m0 = blockIdx.y * 128, n0 = blockIdx.x * 128;
  const int wave = tid >> 6, lane = tid & 63;
  const int wm = wave >> 1, wn = wave & 1;
  const int l15 = lane & 15, lh = lane >> 4;
  floatx4 acc[4][4];
#pragma unroll
  for (int i = 0; i < 4; ++i)
#pragma unroll
    for (int j = 0; j < 4; ++j) acc[i][j] = (floatx4){0.f, 0.f, 0.f, 0.f};

  const int ar = tid >> 3, ac = (tid & 7) * 4;
  const int br = tid >> 2, bc = (tid & 3) * 8;
#pragma unroll 1
  for (int k0 = 0; k0 < DD; k0 += 32) {
    float4 av[4];
#pragma unroll
    for (int p = 0; p < 4; ++p)
      av[p] = *(const float4*)(A + (size_t)(m0 + ar + p * 32) * DD + k0 + ac);
    uint4 bv0 = *(const uint4*)(Wt + (size_t)(n0 + br) * DD + k0 + bc);
    uint4 bv1 = *(const uint4*)(Wt + (size_t)(n0 + br + 64) * DD + k0 + bc);
    __syncthreads();
#pragma unroll
    for (int p = 0; p < 4; ++p) {
      ushort4 w4;
      w4.x = f2bf(av[p].x); w4.y = f2bf(av[p].y);
      w4.z = f2bf(av[p].z); w4.w = f2bf(av[p].w);
      *(ushort4*)&Al[(ar + p * 32) * 40 + ac] = w4;
    }
    *(uint4*)&Bl[br * 40 + bc] = bv0;
    *(uint4*)&Bl[(br + 64) * 40 + bc] = bv1;
    __syncthreads();
    U4S8 af[4], bfr[4];
#pragma unroll
    for (int mf = 0; mf < 4; ++mf)
      af[mf].u4 = *(const uint4*)&Al[(wm * 64 + mf * 16 + l15) * 40 + lh * 8];
#pragma unroll
    for (int nf = 0; nf < 4; ++nf)
      bfr[nf].u4 = *(const uint4*)&Bl[(wn * 64 + nf * 16 + l15) * 40 + lh * 8];
#pragma unroll
    for (int mf = 0; mf < 4; ++mf)
#pragma unroll
      for (int nf = 0; nf < 4; ++nf)
        acc[mf][nf] = __builtin_amdgcn_mfma_f32_16x16x32_bf16(
            af[mf].s8, bfr[nf].s8, acc[mf][nf], 0, 0, 0);
  }
#pragma unroll
  for (int nf = 0; nf < 4; ++nf) {
    int n = n0 + wn * 64 + nf * 16 + l15;
    float bn = bias[n];
#pragma unroll
    for (int mf = 0; mf < 4; ++mf) {
      int row = m0 + wm * 64 + mf * 16 + lh * 4;
      size_t base = (size_t)row * NT + n;
#pragma unroll
      for (int e = 0; e < 4; ++e)
        C[base + (size_t)e * NT] = f2bf(acc[mf][nf][e] + bn);
    }
  }
}

// ---------------- scan: round-7 proven structure; ONLY change vs round 7:
// the drain barrier covers ONLY the publish stores — hout store and next-step
// prefetch are issued AFTER the flag store (their latency hides under the
// next step's spin/A-load/MFMA window instead of sitting in the drain).
__global__ __launch_bounds__(512, 1)
void scan_k(const unsigned short* __restrict__ gx,
            const uint4* __restrict__ Wsc,
            const float* __restrict__ xin,
            float* __restrict__ hout,
            float* __restrict__ cbuf,           // [64][512] f32
            unsigned short* __restrict__ xbu,   // [2][64][512] bf16
            unsigned int* __restrict__ flags,   // [8 bg][8 dg] monotonic
            int reverse, unsigned int step_base) {
  __shared__ float pd[8192];                    // 32 KiB partials
  const int tid = threadIdx.x;
  const int bg = blockIdx.x & 7;
  const int dg = blockIdx.x >> 3;
  const int lane = tid & 63;
  const int w = tid >> 6;
  const int batch = bg * 8 + w;
  const int dim = dg * 64 + lane;

  uint4 Wf[16];
  {
    const uint4* ws = Wsc + (size_t)dg * 8192;
#pragma unroll
    for (int f = 0; f < 16; ++f)
      Wf[f] = ws[(size_t)(w * 16 + f) * 64 + lane];
  }
  float c_reg = cbuf[batch * DD + dim];
  int t0 = reverse ? (LL - 1) : 0;
  size_t r0 = (size_t)t0 * BB + batch;
  float g_i = bf2f(gx[r0 * NT + dim]);
  float g_f = bf2f(gx[r0 * NT + 512 + dim]);
  float g_c = bf2f(gx[r0 * NT + 1024 + dim]);
  float x_v = xin[r0 * DD + dim];
  const int arow = lane & 7, lh = lane >> 4;

#pragma unroll 1
  for (int s = 0; s < LL; ++s) {
    unsigned int need = step_base + (unsigned int)s;
    // ---- per-wave gate: partner block (bg, w) has published step s-1 ----
    {
      const unsigned int* f = flags + bg * 8 + w;
      while (__hip_atomic_load(f, __ATOMIC_RELAXED, __HIP_MEMORY_SCOPE_AGENT) < need)
        __builtin_amdgcn_s_sleep(1);
    }
    // ---- A-frags direct from exchange buffer, parity (s+1)&1 ----
    const ull* src = (const ull*)xbu + (size_t)(((s + 1) & 1)) * 8192;
    int ai = (bg * 8 + arow) * 128 + w * 16 + 2 * lh;
    ull v0 = __hip_atomic_load(&src[ai],     __ATOMIC_RELAXED, __HIP_MEMORY_SCOPE_AGENT);
    ull v1 = __hip_atomic_load(&src[ai + 1], __ATOMIC_RELAXED, __HIP_MEMORY_SCOPE_AGENT);
    ull v2 = __hip_atomic_load(&src[ai + 8], __ATOMIC_RELAXED, __HIP_MEMORY_SCOPE_AGENT);
    ull v3 = __hip_atomic_load(&src[ai + 9], __ATOMIC_RELAXED, __HIP_MEMORY_SCOPE_AGENT);
    // ---- MFMA partials over this wave's K-slice ----
    U4S8 A0, A1;
    A0.u4 = make_uint4((unsigned int)v0, (unsigned int)(v0 >> 32),
                       (unsigned int)v1, (unsigned int)(v1 >> 32));
    A1.u4 = make_uint4((unsigned int)v2, (unsigned int)(v2 >> 32),
                       (unsigned int)v3, (unsigned int)(v3 >> 32));
#pragma unroll
    for (int ct = 0; ct < 8; ++ct) {
      U4S8 B0, B1; B0.u4 = Wf[ct * 2]; B1.u4 = Wf[ct * 2 + 1];
      floatx4 acc = __builtin_amdgcn_mfma_f32_16x16x32_bf16(
          A0.s8, B0.s8, (floatx4){0.f, 0.f, 0.f, 0.f}, 0, 0, 0);
      acc = __builtin_amdgcn_mfma_f32_16x16x32_bf16(A1.s8, B1.s8, acc, 0, 0, 0);
      if (lane < 32) {
        int colb = ct * 16 + (lane & 15);
        int rb = (lane >> 4) * 4;
#pragma unroll
        for (int e = 0; e < 4; ++e)
          pd[(w * 8 + rb + e) * 128 + colb] = acc[e];
      }
    }
    __syncthreads();
    // ---- reduce + gates (wave w owns batch bg*8+w, dim = dg*64+lane) ----
    float gsi = 0.f, gsf = 0.f;
#pragma unroll
    for (int ww = 0; ww < 8; ++ww) {
      gsi += pd[(ww * 8 + w) * 128 + lane];
      gsf += pd[(ww * 8 + w) * 128 + 64 + lane];
    }
    float iv = 1.f / (1.f + __expf(-(g_i + gsi)));
    float fv = 1.f / (1.f + __expf(-(g_f + gsf)));
    float cn = fmaf(fv, c_reg, iv * g_c);
    // ---- publish ONLY (2B relaxed agent store; 128B contiguous per wave) ----
    __hip_atomic_store(xbu + (size_t)((s & 1)) * 32768 + batch * DD + dim,
                       f2bf(cn), __ATOMIC_RELAXED, __HIP_MEMORY_SCOPE_AGENT);
    __syncthreads();   // vmcnt(0) drain: publishes device-visible (nothing else pending)
    if (tid == 0)
      __hip_atomic_store(&flags[bg * 8 + dg], need + 1u,
                         __ATOMIC_RELAXED, __HIP_MEMORY_SCOPE_AGENT);
    // ---- off-critical tail AFTER the flag: hout + next-step prefetch ----
    int t = reverse ? (LL - 1 - s) : s;
    size_t rowg = (size_t)t * BB + batch;
    hout[rowg * DD + dim] = tanhf(cn) + x_v;
    c_reg = cn;
    int sn = (s + 1 < LL) ? s + 1 : s;
    int tn = reverse ? (LL - 1 - sn) : sn;
    size_t rn = (size_t)tn * BB + batch;
    g_i = bf2f(gx[rn * NT + dim]);
    g_f = bf2f(gx[rn * NT + 512 + dim]);
    g_c = bf2f(gx[rn * NT + 1024 + dim]);
    x_v = xin[rn * DD + dim];
  }
  cbuf[batch * DD + dim] = c_reg;
}

extern "C" void kernel_launch(void* const* d_in, const int* in_sizes, int n_in,
                              void* d_out, int out_size, void* d_ws, size_t ws_size,
                              hipStream_t stream) {
  const int* xs = (const int*)d_in[0];
  const float* emb = (const float*)d_in[1];
  const float* Wx = (const float*)d_in[2];
  const float* Wc = (const float*)d_in[3];
  const float* bias = (const float*)d_in[4];
  float* out = (float*)d_out;
  char* ws = (char*)d_ws;

  unsigned short* gx = (unsigned short*)ws;                          // 96 MiB
  float* xB = (float*)(ws + (size_t)100663296);                      // 64 MiB
  unsigned int* Wp = (unsigned int*)(ws + (size_t)167772160);        // 4 MiB
  float* cbuf = (float*)(ws + (size_t)171966464);                    // 128 KiB
  unsigned short* xbu = (unsigned short*)(ws + (size_t)172097536);   // 128 KiB
  unsigned int* flags = (unsigned int*)(ws + (size_t)172228608);     // 256 B
  unsigned short* Wxp = (unsigned short*)(ws + (size_t)172229632);   // 6 MiB
  const size_t NEED = 178521088ull;
  const bool use_mfma_gemm = (ws_size >= NEED);

  hipMemsetAsync(cbuf, 0, 131072, stream);
  hipMemsetAsync(xbu, 0, 131072, stream);    // seed parity-1 with bf16(c0)=0
  hipMemsetAsync(flags, 0, 256, stream);
  pack_wc_k<<<4096, 256, 0, stream>>>(Wc, Wp);
  if (use_mfma_gemm)
    pack_wx_k<<<dim3(8, 24, 4), 256, 0, stream>>>(Wx, Wxp);
  gather_k<<<MROWS * 128 / 256, 256, 0, stream>>>(xs, emb, out);

  for (int s = 0; s < 4; ++s) {
    const float* xin = (s % 2 == 0) ? out : xB;
    float* xout = (s % 2 == 0) ? xB : out;
    if (use_mfma_gemm)
      gemm_m_k<<<dim3(NT / 128, MROWS / 128), 256, 0, stream>>>(
          xin, Wxp + (size_t)s * NT * DD, bias + (size_t)s * NT, gx);
    else
      gemm_k<<<dim3(NT / 128, MROWS / 128), 256, 0, stream>>>(
          xin, Wx + (size_t)s * DD * NT, bias + (size_t)s * NT, gx);
    scan_k<<<64, 512, 0, stream>>>(
        gx, (const uint4*)(Wp + (size_t)s * 262144), xin, xout, cbuf, xbu, flags,
        s & 1, (unsigned int)(s * 512));
  }
}